// Round 6
// baseline (16515.080 us; speedup 1.0000x reference)
//
#include <hip/hip_runtime.h>
#include <math.h>

#define VCAB 80
#define EDIM 8
#define HDIM 256
#define BAT 2048
#define SEQ 256
#define BT 8            // batch rows per workgroup
#define NWG (BAT/BT)    // 256 workgroups
#define NTHR 1024       // 2 K-groups x 2 row-halves x 256 units

// ws layout (floats)
#define W0T_K 264                 // E + H
#define W1T_K 512                 // H + H
#define W0T_OFF 0
#define W1T_OFF (W0T_K*1024)              // 270336
#define BIAS0_OFF (W1T_OFF + W1T_K*1024)  // 794624
#define BIAS1_OFF (BIAS0_OFF + 1024)
#define WS_FLOATS (BIAS1_OFF + 1024)      // 796672 floats ~ 3.04 MB

// Pre-transpose weights into gate-interleaved layout:
// WT[k][unit*4+g] = W[g*H+unit][k]  (g in {i,f,g,o} order, PyTorch LSTM order)
// so each thread's float4 load at [k*1024 + 4*utid] yields (i,f,g,o) of unit utid.
__global__ void prep_kernel(const float* __restrict__ Wih0, const float* __restrict__ Whh0,
                            const float* __restrict__ bih0, const float* __restrict__ bhh0,
                            const float* __restrict__ Wih1, const float* __restrict__ Whh1,
                            const float* __restrict__ bih1, const float* __restrict__ bhh1,
                            float* __restrict__ ws) {
  int idx = blockIdx.x * 256 + threadIdx.x;
  if (idx < W0T_K * 1024) {
    int k = idx >> 10, n2 = idx & 1023;
    int unit = n2 >> 2, g = n2 & 3, r = g * HDIM + unit;
    float v = (k < EDIM) ? Wih0[r * EDIM + k] : Whh0[r * HDIM + (k - EDIM)];
    ws[W0T_OFF + idx] = v;
  } else if (idx < W0T_K * 1024 + W1T_K * 1024) {
    int i2 = idx - W0T_K * 1024;
    int k = i2 >> 10, n2 = i2 & 1023;
    int unit = n2 >> 2, g = n2 & 3, r = g * HDIM + unit;
    float v = (k < HDIM) ? Wih1[r * HDIM + k] : Whh1[r * HDIM + (k - HDIM)];
    ws[W1T_OFF + i2] = v;
  } else if (idx < W0T_K * 1024 + W1T_K * 1024 + 1024) {
    int n2 = idx - (W0T_K * 1024 + W1T_K * 1024);
    int unit = n2 >> 2, g = n2 & 3, r = g * HDIM + unit;
    ws[BIAS0_OFF + n2] = bih0[r] + bhh0[r];
  } else if (idx < W0T_K * 1024 + W1T_K * 1024 + 2048) {
    int n2 = idx - (W0T_K * 1024 + W1T_K * 1024 + 1024);
    int unit = n2 >> 2, g = n2 & 3, r = g * HDIM + unit;
    ws[BIAS1_OFF + n2] = bih1[r] + bhh1[r];
  }
}

__device__ __forceinline__ float sigm(float x) {
  return 1.0f / (1.0f + __expf(-x));
}
__device__ __forceinline__ float tanh_f(float x) {
  float ax = fabsf(x);
  float e = __expf(-2.0f * ax);
  float t = 1.0f - 2.0f * e / (1.0f + e);
  return copysignf(t, x);
}

#define FMA4(A, HS, W) \
  A.x += (HS) * (W).x; A.y += (HS) * (W).y; A.z += (HS) * (W).z; A.w += (HS) * (W).w;

// One workgroup owns BT=8 batch rows for the entire sequence.
// 1024 threads = (rh: row-half) x (kgrp: K-half) x (utid: 256 units).
// Thread (rh,kgrp,utid) accumulates gates of unit utid for rows rh*4..rh*4+3
// over its half of the reduction dim. kgrp=1 deposits partials in LDS;
// kgrp=0 reduces + activations and owns c-state for its 4 rows.
// Both rowhalves load identical weight addresses concurrently -> L1 hit,
// so per-WG L2 weight traffic is unchanged vs the 512-thread version.
__global__ __launch_bounds__(NTHR, 4) void lstm_kernel(
    const int* __restrict__ x, const float* __restrict__ emb,
    const float* __restrict__ ws,
    const float* __restrict__ fcw, const float* __restrict__ fcb,
    float* __restrict__ out) {
  __shared__ float inp0[BT][W0T_K];   // [e(8) | h0(256)] per row        8448 B
  __shared__ float inp1[BT][W1T_K];   // [h0new(256) | h1(256)] per row 16384 B
  __shared__ float4 red[BT][HDIM];    // kgrp=1 partial gate sums       32768 B

  const int tid = threadIdx.x;
  const int utid = tid & 255;         // unit index
  const int kgrp = (tid >> 8) & 1;    // K-half
  const int rh = tid >> 9;            // row-half
  const int rbase = rh * 4;           // rows rbase..rbase+3
  const int bg = blockIdx.x * BT;
  const float4* __restrict__ W0 = (const float4*)(ws + W0T_OFF);
  const float4* __restrict__ W1 = (const float4*)(ws + W1T_OFF);

  float c0[4], c1[4];
#pragma unroll
  for (int j = 0; j < 4; j++) { c0[j] = 0.f; c1[j] = 0.f; }
  if (kgrp == 0) {
#pragma unroll
    for (int j = 0; j < 4; j++) {
      inp0[rbase + j][EDIM + utid] = 0.f;
      inp1[rbase + j][utid] = 0.f;
      inp1[rbase + j][HDIM + utid] = 0.f;
    }
  }
  const float4 bias0 = ((const float4*)(ws + BIAS0_OFF))[utid];
  const float4 bias1 = ((const float4*)(ws + BIAS1_OFF))[utid];
  __syncthreads();

  for (int t = 0; t < SEQ; t++) {
    // stage embeddings for this step: inp0[b][0..7]
    if (tid < BT * EDIM) {
      int b = tid >> 3, d = tid & 7;
      int xv = x[(bg + b) * SEQ + t];
      inp0[b][d] = emb[xv * EDIM + d];
    }
    __syncthreads();

    // ---- layer 0: gates[8 x 1024] = inp0[8 x 264] @ W0T, K split 132/132
    float4 acc[4];
#pragma unroll
    for (int j = 0; j < 4; j++)
      acc[j] = (kgrp == 0) ? bias0 : make_float4(0.f, 0.f, 0.f, 0.f);
    {
      const int kbase = kgrp * (W0T_K / 2);   // 0 or 132 (528 B, 16B-aligned)
#pragma unroll 3
      for (int i = 0; i < W0T_K / 8; i++) {   // 33 iters of 4 k-steps
        const int k = kbase + 4 * i;
        float4 wa = W0[(k + 0) * 256 + utid];
        float4 wb = W0[(k + 1) * 256 + utid];
        float4 wc = W0[(k + 2) * 256 + utid];
        float4 wd = W0[(k + 3) * 256 + utid];
#pragma unroll
        for (int j = 0; j < 4; j++) {
          float4 hv = *(const float4*)&inp0[rbase + j][k];
          FMA4(acc[j], hv.x, wa); FMA4(acc[j], hv.y, wb);
          FMA4(acc[j], hv.z, wc); FMA4(acc[j], hv.w, wd);
        }
      }
    }
    if (kgrp == 1) {
#pragma unroll
      for (int j = 0; j < 4; j++) red[rbase + j][utid] = acc[j];
    }
    __syncthreads();   // partials visible; all inp0 reads complete
    if (kgrp == 0) {
#pragma unroll
      for (int j = 0; j < 4; j++) {
        float4 p = red[rbase + j][utid];
        float ig = sigm(acc[j].x + p.x), fg = sigm(acc[j].y + p.y);
        float gg = tanh_f(acc[j].z + p.z), og = sigm(acc[j].w + p.w);
        c0[j] = fg * c0[j] + ig * gg;
        float h = og * tanh_f(c0[j]);
        inp0[rbase + j][EDIM + utid] = h;   // h0 input for next step
        inp1[rbase + j][utid] = h;          // layer-1 input this step
      }
    }
    __syncthreads();   // h0new visible; red free for reuse

    // ---- layer 1: gates[8 x 1024] = inp1[8 x 512] @ W1T, K split 256/256
#pragma unroll
    for (int j = 0; j < 4; j++)
      acc[j] = (kgrp == 0) ? bias1 : make_float4(0.f, 0.f, 0.f, 0.f);
    {
      const int kbase = kgrp * (W1T_K / 2);   // 0 or 256
#pragma unroll 4
      for (int i = 0; i < W1T_K / 8; i++) {   // 64 iters of 4 k-steps
        const int k = kbase + 4 * i;
        float4 wa = W1[(k + 0) * 256 + utid];
        float4 wb = W1[(k + 1) * 256 + utid];
        float4 wc = W1[(k + 2) * 256 + utid];
        float4 wd = W1[(k + 3) * 256 + utid];
#pragma unroll
        for (int j = 0; j < 4; j++) {
          float4 hv = *(const float4*)&inp1[rbase + j][k];
          FMA4(acc[j], hv.x, wa); FMA4(acc[j], hv.y, wb);
          FMA4(acc[j], hv.z, wc); FMA4(acc[j], hv.w, wd);
        }
      }
    }
    if (kgrp == 1) {
#pragma unroll
      for (int j = 0; j < 4; j++) red[rbase + j][utid] = acc[j];
    }
    __syncthreads();   // partials visible; all inp1 reads complete
    if (kgrp == 0) {
#pragma unroll
      for (int j = 0; j < 4; j++) {
        float4 p = red[rbase + j][utid];
        float ig = sigm(acc[j].x + p.x), fg = sigm(acc[j].y + p.y);
        float gg = tanh_f(acc[j].z + p.z), og = sigm(acc[j].w + p.w);
        c1[j] = fg * c1[j] + ig * gg;
        inp1[rbase + j][HDIM + utid] = og * tanh_f(c1[j]);
      }
    }
    __syncthreads();   // h1new visible for next step's layer-1 / epilogue
  }

  // ---- FC: logits[bg+b][v] = h1[b] . fcw[v] + fcb[v] ----
  for (int o = tid; o < BT * VCAB; o += NTHR) {
    int b = o / VCAB, v = o - b * VCAB;
    float a = fcb[v];
    const float4* wrow = (const float4*)(fcw + v * HDIM);
    const float4* hrow = (const float4*)&inp1[b][HDIM];
#pragma unroll 4
    for (int k = 0; k < HDIM / 4; k++) {
      float4 w = wrow[k];
      float4 h = hrow[k];
      a += h.x * w.x + h.y * w.y + h.z * w.z + h.w * w.w;
    }
    out[(bg + b) * VCAB + v] = a;
  }

  // ---- final h, c states: out layout = [logits | h(2,B,H) | c(2,B,H)] ----
  // c0/c1 live only in kgrp=0 registers (4 rows per rowhalf).
  if (kgrp == 0) {
    float* outh = out + BAT * VCAB;
    float* outc = outh + 2 * BAT * HDIM;
#pragma unroll
    for (int j = 0; j < 4; j++) {
      int b = rbase + j;
      outh[0 * BAT * HDIM + (bg + b) * HDIM + utid] = inp0[b][EDIM + utid];
      outh[1 * BAT * HDIM + (bg + b) * HDIM + utid] = inp1[b][HDIM + utid];
      outc[0 * BAT * HDIM + (bg + b) * HDIM + utid] = c0[j];
      outc[1 * BAT * HDIM + (bg + b) * HDIM + utid] = c1[j];
    }
  }
}

extern "C" void kernel_launch(void* const* d_in, const int* in_sizes, int n_in,
                              void* d_out, int out_size, void* d_ws, size_t ws_size,
                              hipStream_t stream) {
  const int*   x    = (const int*)d_in[0];
  const float* emb  = (const float*)d_in[1];
  const float* Wih0 = (const float*)d_in[2];
  const float* Whh0 = (const float*)d_in[3];
  const float* bih0 = (const float*)d_in[4];
  const float* bhh0 = (const float*)d_in[5];
  const float* Wih1 = (const float*)d_in[6];
  const float* Whh1 = (const float*)d_in[7];
  const float* bih1 = (const float*)d_in[8];
  const float* bhh1 = (const float*)d_in[9];
  const float* fcw  = (const float*)d_in[10];
  const float* fcb  = (const float*)d_in[11];
  float* out = (float*)d_out;
  float* ws  = (float*)d_ws;

  prep_kernel<<<(WS_FLOATS + 255) / 256, 256, 0, stream>>>(
      Wih0, Whh0, bih0, bhh0, Wih1, Whh1, bih1, bhh1, ws);
  lstm_kernel<<<NWG, NTHR, 0, stream>>>(x, emb, ws, fcw, fcb, out);
}

// Round 7
// 13700.255 us; speedup vs baseline: 1.2055x; 1.2055x over previous
//
#include <hip/hip_runtime.h>
#include <math.h>

#define VCAB 80
#define EDIM 8
#define HDIM 256
#define BAT 2048
#define SEQ 256
#define BT 8            // batch rows per workgroup
#define NWG (BAT/BT)    // 256 workgroups = 1 per CU
#define NTHR 1024       // 4 K-groups x 256 units
#define KG 4            // K-split ways

// ws layout (floats). L0 K padded 264 -> 272 so each K-quarter (68) is
// float4-aligned; pad weight rows are zero, pad input floats zeroed once.
#define W0T_KP 272
#define W1T_K 512
#define W0T_OFF 0
#define W1T_OFF (W0T_KP*1024)             // 278528
#define BIAS0_OFF (W1T_OFF + W1T_K*1024)  // 802816
#define BIAS1_OFF (BIAS0_OFF + 1024)
#define WS_FLOATS (BIAS1_OFF + 1024)      // 804864 floats ~ 3.07 MB

// Gate-interleaved transpose: WT[k][unit*4+g] = W[g*H+unit][k]
// (g in i,f,g,o order) so a float4 load at [k*1024+4*utid] = 4 gates of unit utid.
__global__ void prep_kernel(const float* __restrict__ Wih0, const float* __restrict__ Whh0,
                            const float* __restrict__ bih0, const float* __restrict__ bhh0,
                            const float* __restrict__ Wih1, const float* __restrict__ Whh1,
                            const float* __restrict__ bih1, const float* __restrict__ bhh1,
                            float* __restrict__ ws) {
  int idx = blockIdx.x * 256 + threadIdx.x;
  if (idx < W0T_KP * 1024) {
    int k = idx >> 10, n2 = idx & 1023;
    int unit = n2 >> 2, g = n2 & 3, r = g * HDIM + unit;
    float v = (k < EDIM) ? Wih0[r * EDIM + k]
            : (k < EDIM + HDIM) ? Whh0[r * HDIM + (k - EDIM)]
            : 0.f;                                   // zero pad rows 264..271
    ws[W0T_OFF + idx] = v;
  } else if (idx < W0T_KP * 1024 + W1T_K * 1024) {
    int i2 = idx - W0T_KP * 1024;
    int k = i2 >> 10, n2 = i2 & 1023;
    int unit = n2 >> 2, g = n2 & 3, r = g * HDIM + unit;
    float v = (k < HDIM) ? Wih1[r * HDIM + k] : Whh1[r * HDIM + (k - HDIM)];
    ws[W1T_OFF + i2] = v;
  } else if (idx < W0T_KP * 1024 + W1T_K * 1024 + 1024) {
    int n2 = idx - (W0T_KP * 1024 + W1T_K * 1024);
    int unit = n2 >> 2, g = n2 & 3, r = g * HDIM + unit;
    ws[BIAS0_OFF + n2] = bih0[r] + bhh0[r];
  } else if (idx < W0T_KP * 1024 + W1T_K * 1024 + 2048) {
    int n2 = idx - (W0T_KP * 1024 + W1T_K * 1024 + 1024);
    int unit = n2 >> 2, g = n2 & 3, r = g * HDIM + unit;
    ws[BIAS1_OFF + n2] = bih1[r] + bhh1[r];
  }
}

__device__ __forceinline__ float sigm(float x) {
  return 1.0f / (1.0f + __expf(-x));
}
__device__ __forceinline__ float tanh_f(float x) {
  float ax = fabsf(x);
  float e = __expf(-2.0f * ax);
  float t = 1.0f - 2.0f * e / (1.0f + e);
  return copysignf(t, x);
}

#define FMA4(A, HS, W) \
  A.x += (HS) * (W).x; A.y += (HS) * (W).y; A.z += (HS) * (W).z; A.w += (HS) * (W).w;

// One WG owns BT=8 rows for the whole sequence. 1024 threads = 4 K-groups
// (kgrp) x 256 units (utid). Every thread keeps all 8 rows (32:1 FMA:load,
// same as the 14.7ms R5 kernel) over its K-QUARTER -> total weight-load
// instructions per WG unchanged vs R5 (R6 lesson: never replicate weight
// loads to gain waves). kgrp 1..3 deposit partials in red[]; kgrp 0 reduces,
// applies activations, owns c-state. 4 barriers/step. LDS 123KB -> 1 WG/CU.
__global__ __launch_bounds__(NTHR, 4) void lstm_kernel(
    const int* __restrict__ x, const float* __restrict__ emb,
    const float* __restrict__ ws,
    const float* __restrict__ fcw, const float* __restrict__ fcb,
    float* __restrict__ out) {
  __shared__ float inp0[BT][W0T_KP];       // [e(8)|h0(256)|pad(8)]      8704 B
  __shared__ float inp1[BT][W1T_K];        // [h0new(256)|h1(256)]      16384 B
  __shared__ float4 red[KG - 1][BT][HDIM]; // kgrp1..3 partials         98304 B

  const int tid = threadIdx.x;
  const int utid = tid & 255;        // unit index
  const int kgrp = tid >> 8;         // K-quarter 0..3
  const int bg = blockIdx.x * BT;
  const float4* __restrict__ W0 = (const float4*)(ws + W0T_OFF);
  const float4* __restrict__ W1 = (const float4*)(ws + W1T_OFF);

  float c0[BT], c1[BT];
#pragma unroll
  for (int b = 0; b < BT; b++) { c0[b] = 0.f; c1[b] = 0.f; }
  if (kgrp == 0) {
#pragma unroll
    for (int b = 0; b < BT; b++) {
      inp0[b][EDIM + utid] = 0.f;
      inp1[b][utid] = 0.f;
      inp1[b][HDIM + utid] = 0.f;
    }
  }
  if (tid < BT * EDIM) inp0[tid >> 3][264 + (tid & 7)] = 0.f;  // zero K-pad once
  const float4 bias0 = ((const float4*)(ws + BIAS0_OFF))[utid];
  const float4 bias1 = ((const float4*)(ws + BIAS1_OFF))[utid];
  __syncthreads();

  for (int t = 0; t < SEQ; t++) {
    // stage embeddings: inp0[b][0..7] (kgrp0 threads only)
    if (tid < BT * EDIM) {
      int b = tid >> 3, d = tid & 7;
      int xv = x[(bg + b) * SEQ + t];
      inp0[b][d] = emb[xv * EDIM + d];
    }
    __syncthreads();   // A: emb visible

    // ---- layer 0: gates[8 x 1024] = inp0[8 x 272] @ W0T, K quarter = 68
    float4 acc[BT];
#pragma unroll
    for (int b = 0; b < BT; b++) acc[b] = make_float4(0.f, 0.f, 0.f, 0.f);
    {
      const int kbase = kgrp * (W0T_KP / KG);   // 0,68,136,204 (16B-aligned)
#pragma unroll 2
      for (int i = 0; i < W0T_KP / KG / 4; i++) {  // 17 iters of 4 k-steps
        const int k = kbase + 4 * i;
        float4 wa = W0[(k + 0) * 256 + utid];
        float4 wb = W0[(k + 1) * 256 + utid];
        float4 wc = W0[(k + 2) * 256 + utid];
        float4 wd = W0[(k + 3) * 256 + utid];
#pragma unroll
        for (int b = 0; b < BT; b++) {
          float4 hv = *(const float4*)&inp0[b][k];
          FMA4(acc[b], hv.x, wa); FMA4(acc[b], hv.y, wb);
          FMA4(acc[b], hv.z, wc); FMA4(acc[b], hv.w, wd);
        }
      }
    }
    if (kgrp > 0) {
#pragma unroll
      for (int b = 0; b < BT; b++) red[kgrp - 1][b][utid] = acc[b];
    }
    __syncthreads();   // B: partials visible; all inp0 reads complete
    if (kgrp == 0) {
#pragma unroll
      for (int b = 0; b < BT; b++) {
        float4 p0 = red[0][b][utid], p1 = red[1][b][utid], p2 = red[2][b][utid];
        float gx = acc[b].x + p0.x + p1.x + p2.x + bias0.x;
        float gy = acc[b].y + p0.y + p1.y + p2.y + bias0.y;
        float gz = acc[b].z + p0.z + p1.z + p2.z + bias0.z;
        float gw = acc[b].w + p0.w + p1.w + p2.w + bias0.w;
        float ig = sigm(gx), fg = sigm(gy), gg = tanh_f(gz), og = sigm(gw);
        c0[b] = fg * c0[b] + ig * gg;
        float h = og * tanh_f(c0[b]);
        inp0[b][EDIM + utid] = h;   // h0 input for next step
        inp1[b][utid] = h;          // layer-1 input this step
      }
    }
    __syncthreads();   // C: h0new visible; red free for reuse

    // ---- layer 1: gates[8 x 1024] = inp1[8 x 512] @ W1T, K quarter = 128
#pragma unroll
    for (int b = 0; b < BT; b++) acc[b] = make_float4(0.f, 0.f, 0.f, 0.f);
    {
      const int kbase = kgrp * (W1T_K / KG);   // 0,128,256,384
#pragma unroll 2
      for (int i = 0; i < W1T_K / KG / 4; i++) {  // 32 iters of 4 k-steps
        const int k = kbase + 4 * i;
        float4 wa = W1[(k + 0) * 256 + utid];
        float4 wb = W1[(k + 1) * 256 + utid];
        float4 wc = W1[(k + 2) * 256 + utid];
        float4 wd = W1[(k + 3) * 256 + utid];
#pragma unroll
        for (int b = 0; b < BT; b++) {
          float4 hv = *(const float4*)&inp1[b][k];
          FMA4(acc[b], hv.x, wa); FMA4(acc[b], hv.y, wb);
          FMA4(acc[b], hv.z, wc); FMA4(acc[b], hv.w, wd);
        }
      }
    }
    if (kgrp > 0) {
#pragma unroll
      for (int b = 0; b < BT; b++) red[kgrp - 1][b][utid] = acc[b];
    }
    __syncthreads();   // D: partials visible; all inp1 reads complete
    if (kgrp == 0) {
#pragma unroll
      for (int b = 0; b < BT; b++) {
        float4 p0 = red[0][b][utid], p1 = red[1][b][utid], p2 = red[2][b][utid];
        float gx = acc[b].x + p0.x + p1.x + p2.x + bias1.x;
        float gy = acc[b].y + p0.y + p1.y + p2.y + bias1.y;
        float gz = acc[b].z + p0.z + p1.z + p2.z + bias1.z;
        float gw = acc[b].w + p0.w + p1.w + p2.w + bias1.w;
        float ig = sigm(gx), fg = sigm(gy), gg = tanh_f(gz), og = sigm(gw);
        c1[b] = fg * c1[b] + ig * gg;
        inp1[b][HDIM + utid] = og * tanh_f(c1[b]);
      }
    }
    __syncthreads();   // end-of-step: h1new ordered before next step's reads
  }

  // ---- FC: logits[bg+b][v] = h1[b] . fcw[v] + fcb[v] ----
  for (int o = tid; o < BT * VCAB; o += NTHR) {
    int b = o / VCAB, v = o - b * VCAB;
    float a = fcb[v];
    const float4* wrow = (const float4*)(fcw + v * HDIM);
    const float4* hrow = (const float4*)&inp1[b][HDIM];
#pragma unroll 4
    for (int k = 0; k < HDIM / 4; k++) {
      float4 w = wrow[k];
      float4 h = hrow[k];
      a += h.x * w.x + h.y * w.y + h.z * w.z + h.w * w.w;
    }
    out[(bg + b) * VCAB + v] = a;
  }

  // ---- final h, c states: out layout = [logits | h(2,B,H) | c(2,B,H)] ----
  // c0/c1 live only in kgrp0 registers.
  if (kgrp == 0) {
    float* outh = out + BAT * VCAB;
    float* outc = outh + 2 * BAT * HDIM;
#pragma unroll
    for (int b = 0; b < BT; b++) {
      outh[0 * BAT * HDIM + (bg + b) * HDIM + utid] = inp0[b][EDIM + utid];
      outh[1 * BAT * HDIM + (bg + b) * HDIM + utid] = inp1[b][HDIM + utid];
      outc[0 * BAT * HDIM + (bg + b) * HDIM + utid] = c0[b];
      outc[1 * BAT * HDIM + (bg + b) * HDIM + utid] = c1[b];
    }
  }
}

extern "C" void kernel_launch(void* const* d_in, const int* in_sizes, int n_in,
                              void* d_out, int out_size, void* d_ws, size_t ws_size,
                              hipStream_t stream) {
  const int*   x    = (const int*)d_in[0];
  const float* emb  = (const float*)d_in[1];
  const float* Wih0 = (const float*)d_in[2];
  const float* Whh0 = (const float*)d_in[3];
  const float* bih0 = (const float*)d_in[4];
  const float* bhh0 = (const float*)d_in[5];
  const float* Wih1 = (const float*)d_in[6];
  const float* Whh1 = (const float*)d_in[7];
  const float* bih1 = (const float*)d_in[8];
  const float* bhh1 = (const float*)d_in[9];
  const float* fcw  = (const float*)d_in[10];
  const float* fcb  = (const float*)d_in[11];
  float* out = (float*)d_out;
  float* ws  = (float*)d_ws;

  prep_kernel<<<(WS_FLOATS + 255) / 256, 256, 0, stream>>>(
      Wih0, Whh0, bih0, bhh0, Wih1, Whh1, bih1, bhh1, ws);
  lstm_kernel<<<NWG, NTHR, 0, stream>>>(x, emb, ws, fcw, fcb, out);
}